// Round 1
// baseline (503.416 us; speedup 1.0000x reference)
//
#include <hip/hip_runtime.h>
#include <hip/hip_bf16.h>

// Problem constants (setup_inputs is fixed: B=16, z_dim=64, H=W=32, M=4096)
#define ZD   64
#define MM   4096
#define NN   16384
#define HWSZ 1024
#define BB   16

typedef __bf16 bf16x8 __attribute__((ext_vector_type(8)));
typedef float  f32x4  __attribute__((ext_vector_type(4)));

#define EMA_C 0.999f
#define EPS_C 1e-8f

// ---------------------------------------------------------------------------
// k_prep_e: convert e -> bf16, en2 = ||ebf16||^2 ; init bmax/dmin/sume
// grid 1024 x 256 : one wave per e-row (4096 rows), lane k holds e[row][k]
// ---------------------------------------------------------------------------
__global__ __launch_bounds__(256) void k_prep_e(const float* __restrict__ e,
                                                __hip_bfloat16* __restrict__ ebf,
                                                float* __restrict__ en2,
                                                unsigned* __restrict__ bmax,
                                                unsigned* __restrict__ dmin,
                                                float* __restrict__ sume) {
    int tid = threadIdx.x;
    int gid = blockIdx.x * 256 + tid;
    if (gid < MM) {              // init accumulators (ws is poisoned each launch)
        bmax[gid] = 0u;          // belong*d >= 0 -> uint-as-float max works
        dmin[gid] = 0x7f800000u; // +inf
        sume[gid] = 0.f;
    }
    int wave = tid >> 6, lane = tid & 63;
    int row = blockIdx.x * 4 + wave;
    if (row < MM) {
        float v = e[row * ZD + lane];
        __hip_bfloat16 b = __float2bfloat16(v);
        ebf[row * ZD + lane] = b;
        float q = __bfloat162float(b);   // norm from quantized value (consistency)
        float s = q * q;
        for (int off = 32; off; off >>= 1) s += __shfl_xor(s, off);
        if (lane == 0) en2[row] = s;
    }
}

// ---------------------------------------------------------------------------
// k_prep_z: LDS tile transpose z[B][ZD][HW] -> zf[N][ZD] bf16, zn2 = ||zf||^2
// grid (16 b, 16 hw-tiles) x 256
// ---------------------------------------------------------------------------
__global__ __launch_bounds__(256) void k_prep_z(const float* __restrict__ z,
                                                __hip_bfloat16* __restrict__ zf,
                                                float* __restrict__ zn2) {
    __shared__ float tile[64][65];   // +1 pad -> 2-way (free) bank aliasing
    __shared__ float part[4][64];
    int b   = blockIdx.x;
    int hw0 = blockIdx.y * 64;
    int tid = threadIdx.x;
    int tx = tid & 63, ty = tid >> 6;
    const float* zp = z + (size_t)b * (ZD * HWSZ);
#pragma unroll
    for (int kk = 0; kk < 16; kk++) {
        int k = kk * 4 + ty;
        tile[k][tx] = zp[(size_t)k * HWSZ + hw0 + tx];  // coalesced 256B/wave
    }
    __syncthreads();
#pragma unroll
    for (int i = 0; i < 16; i++) {   // coalesced bf16 row writes
        int li = tid + i * 256;
        int ln = li >> 6, lk = li & 63;
        int n = b * HWSZ + hw0 + ln;
        zf[(size_t)n * ZD + lk] = __float2bfloat16(tile[lk][ln]);
    }
    // zn2 partials: thread (tx = n_local, ty) sums k = ty + 4*kk
    float s = 0.f;
#pragma unroll
    for (int kk = 0; kk < 16; kk++) {
        float q = __bfloat162float(__float2bfloat16(tile[ty + kk * 4][tx]));
        s += q * q;
    }
    part[ty][tx] = s;
    __syncthreads();
    if (tid < 64) {
        float t = part[0][tid] + part[1][tid] + part[2][tid] + part[3][tid];
        zn2[b * HWSZ + hw0 + tid] = t;
    }
}

// ---------------------------------------------------------------------------
// Pass kernels: block = 256 thr (4 waves, 2x2), block tile 64n x 128m,
// wave tile 32n x 64m = 2x4 MFMA 16x16 tiles, K=64 -> 2 chained mfma each.
// A frag: zf row (lane&15), k = (lane>>4)*8 + j (+32)  -> 16B contiguous
// B frag: e  row (lane&15), same k layout
// D: col = lane&15 (m), row = (lane>>4)*4 + reg (n)
// ---------------------------------------------------------------------------
__global__ __launch_bounds__(256) void k_pass1(const __hip_bfloat16* __restrict__ zf,
                                               const __hip_bfloat16* __restrict__ ebf,
                                               const float* __restrict__ zn2,
                                               const float* __restrict__ en2,
                                               const float* __restrict__ belong,
                                               unsigned* __restrict__ bmax,
                                               unsigned* __restrict__ dmin) {
    int tid = threadIdx.x;
    int wave = tid >> 6, lane = tid & 63;
    int l16 = lane & 15, lq = lane >> 4;
    int wn = wave >> 1, wm = wave & 1;
    int n0 = blockIdx.x * 64 + wn * 32;
    int m0 = blockIdx.y * 128 + wm * 64;

    const bf16x8* zfv = reinterpret_cast<const bf16x8*>(zf);
    const bf16x8* ebv = reinterpret_cast<const bf16x8*>(ebf);

    bf16x8 Af[2][2], Bf[4][2];
#pragma unroll
    for (int i = 0; i < 2; i++)
#pragma unroll
        for (int h = 0; h < 2; h++)
            Af[i][h] = zfv[(size_t)(n0 + i * 16 + l16) * 8 + h * 4 + lq];
#pragma unroll
    for (int j = 0; j < 4; j++)
#pragma unroll
        for (int h = 0; h < 2; h++)
            Bf[j][h] = ebv[(size_t)(m0 + j * 16 + l16) * 8 + h * 4 + lq];

    f32x4 acc[2][4];
#pragma unroll
    for (int i = 0; i < 2; i++)
#pragma unroll
        for (int j = 0; j < 4; j++) {
            acc[i][j] = (f32x4){0.f, 0.f, 0.f, 0.f};
            acc[i][j] = __builtin_amdgcn_mfma_f32_16x16x32_bf16(Af[i][0], Bf[j][0], acc[i][j], 0, 0, 0);
            acc[i][j] = __builtin_amdgcn_mfma_f32_16x16x32_bf16(Af[i][1], Bf[j][1], acc[i][j], 0, 0, 0);
        }

    float zn2v[2][4];
#pragma unroll
    for (int i = 0; i < 2; i++)
#pragma unroll
        for (int r = 0; r < 4; r++)
            zn2v[i][r] = zn2[n0 + i * 16 + lq * 4 + r];

    __shared__ unsigned smax[128], smin[128];
    if (tid < 128) { smax[tid] = 0u; smin[tid] = 0x7f800000u; }
    __syncthreads();

#pragma unroll
    for (int j = 0; j < 4; j++) {
        float en2v = en2[m0 + j * 16 + l16];
        float vmax = 0.f, vmin = 3.4e38f;
#pragma unroll
        for (int i = 0; i < 2; i++)
#pragma unroll
            for (int r = 0; r < 4; r++) {
                float d2 = zn2v[i][r] + en2v - 2.f * acc[i][j][r];
                float d = sqrtf(fmaxf(d2, 0.f));
                int n = n0 + i * 16 + lq * 4 + r;
                float bel = belong[(size_t)n * MM + (m0 + j * 16 + l16)];
                vmax = fmaxf(vmax, bel * d);
                vmin = fminf(vmin, d);
            }
        vmax = fmaxf(vmax, __shfl_xor(vmax, 16));
        vmax = fmaxf(vmax, __shfl_xor(vmax, 32));
        vmin = fminf(vmin, __shfl_xor(vmin, 16));
        vmin = fminf(vmin, __shfl_xor(vmin, 32));
        if (lane < 16) {
            int ml = wm * 64 + j * 16 + lane;
            atomicMax(&smax[ml], __float_as_uint(vmax));
            atomicMin(&smin[ml], __float_as_uint(vmin));
        }
    }
    __syncthreads();
    if (tid < 128) {
        atomicMax(&bmax[blockIdx.y * 128 + tid], smax[tid]);
        atomicMin(&dmin[blockIdx.y * 128 + tid], smin[tid]);
    }
}

// ---------------------------------------------------------------------------
// k_mid: new_max + per-column upper bound (ref) on s = alpha*t, M threads
// t(d) = d^(2/p) if d<nm else d^(2p); monotone-piece lower bound on t:
//   dmin < nm ? min(dmin^(2/p), nm^(2p)) : dmin^(2p)   (exact when dmin>=nm)
// ---------------------------------------------------------------------------
__global__ __launch_bounds__(256) void k_mid(const unsigned* __restrict__ bmax,
                                             const unsigned* __restrict__ dmin,
                                             const float* __restrict__ max_distance,
                                             const float* __restrict__ log_sigma,
                                             const int* __restrict__ pp,
                                             float* __restrict__ nmax,
                                             float* __restrict__ refs) {
    int m = blockIdx.x * 256 + threadIdx.x;
    if (m >= MM) return;
    float bm = __uint_as_float(bmax[m]);
    float dm = __uint_as_float(dmin[m]);
    float nm = fmaxf(EMA_C * max_distance[m] + (1.f - EMA_C) * bm, EPS_C);
    int p = pp[0];
    float tlow;
    if (p == 2) {
        float d4  = (dm * dm) * (dm * dm);
        float nm4 = (nm * nm) * (nm * nm);
        tlow = (dm < nm) ? fminf(dm, nm4) : d4;
    } else {
        float e1 = 2.f / (float)p, e2 = 2.f * (float)p;
        tlow = (dm < nm) ? fminf(powf(dm, e1), powf(nm, e2)) : powf(dm, e2);
    }
    float alpha = -0.5f * expf(-2.f * log_sigma[0]);
    nmax[m] = nm;
    refs[m] = alpha * tlow;   // alpha<0, t>=tlow  =>  s <= ref  (no overflow)
}

// ---------------------------------------------------------------------------
// k_pass2: recompute distances (identical MFMA sequence), transform, and
// accumulate sum_exp[m] += exp(alpha*t - ref[m])
// ---------------------------------------------------------------------------
__global__ __launch_bounds__(256) void k_pass2(const __hip_bfloat16* __restrict__ zf,
                                               const __hip_bfloat16* __restrict__ ebf,
                                               const float* __restrict__ zn2,
                                               const float* __restrict__ en2,
                                               const float* __restrict__ nmax,
                                               const float* __restrict__ refs,
                                               const float* __restrict__ log_sigma,
                                               const int* __restrict__ pp,
                                               float* __restrict__ sume) {
    int tid = threadIdx.x;
    int wave = tid >> 6, lane = tid & 63;
    int l16 = lane & 15, lq = lane >> 4;
    int wn = wave >> 1, wm = wave & 1;
    int n0 = blockIdx.x * 64 + wn * 32;
    int m0 = blockIdx.y * 128 + wm * 64;

    const bf16x8* zfv = reinterpret_cast<const bf16x8*>(zf);
    const bf16x8* ebv = reinterpret_cast<const bf16x8*>(ebf);

    bf16x8 Af[2][2], Bf[4][2];
#pragma unroll
    for (int i = 0; i < 2; i++)
#pragma unroll
        for (int h = 0; h < 2; h++)
            Af[i][h] = zfv[(size_t)(n0 + i * 16 + l16) * 8 + h * 4 + lq];
#pragma unroll
    for (int j = 0; j < 4; j++)
#pragma unroll
        for (int h = 0; h < 2; h++)
            Bf[j][h] = ebv[(size_t)(m0 + j * 16 + l16) * 8 + h * 4 + lq];

    f32x4 acc[2][4];
#pragma unroll
    for (int i = 0; i < 2; i++)
#pragma unroll
        for (int j = 0; j < 4; j++) {
            acc[i][j] = (f32x4){0.f, 0.f, 0.f, 0.f};
            acc[i][j] = __builtin_amdgcn_mfma_f32_16x16x32_bf16(Af[i][0], Bf[j][0], acc[i][j], 0, 0, 0);
            acc[i][j] = __builtin_amdgcn_mfma_f32_16x16x32_bf16(Af[i][1], Bf[j][1], acc[i][j], 0, 0, 0);
        }

    float zn2v[2][4];
#pragma unroll
    for (int i = 0; i < 2; i++)
#pragma unroll
        for (int r = 0; r < 4; r++)
            zn2v[i][r] = zn2[n0 + i * 16 + lq * 4 + r];

    float alpha = -0.5f * expf(-2.f * log_sigma[0]);
    int p = pp[0];
    bool p2 = (p == 2);
    float e1 = 2.f / (float)p, e2 = 2.f * (float)p;

    __shared__ float ssum[128];
    if (tid < 128) ssum[tid] = 0.f;
    __syncthreads();

#pragma unroll
    for (int j = 0; j < 4; j++) {
        float en2v = en2[m0 + j * 16 + l16];
        float nmv = nmax[m0 + j * 16 + l16];
        float rfv = refs[m0 + j * 16 + l16];
        float csum = 0.f;
#pragma unroll
        for (int i = 0; i < 2; i++)
#pragma unroll
            for (int r = 0; r < 4; r++) {
                float d2c = fmaxf(zn2v[i][r] + en2v - 2.f * acc[i][j][r], 0.f);
                float d = sqrtf(d2c);
                float t;
                if (p2) t = (d < nmv) ? d : d2c * d2c;
                else    t = powf(d, (d < nmv) ? e1 : e2);
                csum += expf(alpha * t - rfv);
            }
        csum += __shfl_xor(csum, 16);
        csum += __shfl_xor(csum, 32);
        if (lane < 16) atomicAdd(&ssum[wm * 64 + j * 16 + lane], csum);
    }
    __syncthreads();
    if (tid < 128) atomicAdd(&sume[blockIdx.y * 128 + tid], ssum[tid]);
}

// ---------------------------------------------------------------------------
// k_final: loss = -mean(ref + log(sum_exp)) + z_dim * log_sigma
// ---------------------------------------------------------------------------
__global__ __launch_bounds__(256) void k_final(const float* __restrict__ refs,
                                               const float* __restrict__ sume,
                                               const float* __restrict__ log_sigma,
                                               float* __restrict__ out) {
    __shared__ float red[4];
    int tid = threadIdx.x;
    float a = 0.f;
    for (int m = tid; m < MM; m += 256)
        a += refs[m] + logf(fmaxf(sume[m], 1e-30f));
    for (int off = 32; off; off >>= 1) a += __shfl_xor(a, off);
    int wave = tid >> 6, lane = tid & 63;
    if (lane == 0) red[wave] = a;
    __syncthreads();
    if (tid == 0) {
        float t = red[0] + red[1] + red[2] + red[3];
        out[0] = -t / (float)MM + (float)ZD * log_sigma[0];
    }
}

// ---------------------------------------------------------------------------
extern "C" void kernel_launch(void* const* d_in, const int* in_sizes, int n_in,
                              void* d_out, int out_size, void* d_ws, size_t ws_size,
                              hipStream_t stream) {
    const float* z            = (const float*)d_in[0];
    const float* e            = (const float*)d_in[1];
    const float* belong       = (const float*)d_in[2];
    const float* log_sigma    = (const float*)d_in[3];
    const float* max_distance = (const float*)d_in[4];
    const int*   pp           = (const int*)d_in[5];
    float* out = (float*)d_out;

    char* ws = (char*)d_ws;
    __hip_bfloat16* zf  = (__hip_bfloat16*)(ws + 0);        // 2,097,152 B
    __hip_bfloat16* ebf = (__hip_bfloat16*)(ws + 2097152);  //   524,288 B
    float*    zn2  = (float*)(ws + 2621440);                //    65,536 B
    float*    en2  = (float*)(ws + 2686976);                //    16,384 B
    unsigned* bmax = (unsigned*)(ws + 2703360);             //    16,384 B
    unsigned* dmin = (unsigned*)(ws + 2719744);             //    16,384 B
    float*    nmax = (float*)(ws + 2736128);                //    16,384 B
    float*    refs = (float*)(ws + 2752512);                //    16,384 B
    float*    sume = (float*)(ws + 2768896);                //    16,384 B

    k_prep_e<<<1024, 256, 0, stream>>>(e, ebf, en2, bmax, dmin, sume);
    k_prep_z<<<dim3(BB, HWSZ / 64), 256, 0, stream>>>(z, zf, zn2);
    k_pass1<<<dim3(NN / 64, MM / 128), 256, 0, stream>>>(zf, ebf, zn2, en2, belong, bmax, dmin);
    k_mid<<<MM / 256, 256, 0, stream>>>(bmax, dmin, max_distance, log_sigma, pp, nmax, refs);
    k_pass2<<<dim3(NN / 64, MM / 128), 256, 0, stream>>>(zf, ebf, zn2, en2, nmax, refs, log_sigma, pp, sume);
    k_final<<<1, 256, 0, stream>>>(refs, sume, log_sigma, out);
}

// Round 2
// 484.358 us; speedup vs baseline: 1.0393x; 1.0393x over previous
//
#include <hip/hip_runtime.h>
#include <hip/hip_bf16.h>

// Problem constants (setup_inputs fixed: B=16, z_dim=64, H=W=32, M=4096)
#define ZD   64
#define MM   4096
#define NN   16384
#define HWSZ 1024
#define BB   16

typedef __bf16 bf16x8 __attribute__((ext_vector_type(8)));
typedef float  f32x4  __attribute__((ext_vector_type(4)));

#define EMA_C 0.999f
#define EPS_C 1e-8f

// ---------------------------------------------------------------------------
// k_prep (merged): blocks [0,256): z transpose->bf16 + zn2
//                  blocks [256,1280): e->bf16 + en2 + accumulator init
// ---------------------------------------------------------------------------
__global__ __launch_bounds__(256) void k_prep(const float* __restrict__ z,
                                              const float* __restrict__ e,
                                              __hip_bfloat16* __restrict__ zf,
                                              __hip_bfloat16* __restrict__ ebf,
                                              float* __restrict__ zn2,
                                              float* __restrict__ en2,
                                              unsigned* __restrict__ bmax,
                                              unsigned* __restrict__ dmin,
                                              float* __restrict__ sume) {
    __shared__ float tile[64][65];
    __shared__ float part[4][64];
    int blk = blockIdx.x;
    int tid = threadIdx.x;
    if (blk < 256) {
        // ---- z prep: b = blk>>4, hw-tile = blk&15 ----
        int b   = blk >> 4;
        int hw0 = (blk & 15) * 64;
        int tx = tid & 63, ty = tid >> 6;
        const float* zp = z + (size_t)b * (ZD * HWSZ);
#pragma unroll
        for (int kk = 0; kk < 16; kk++) {
            int k = kk * 4 + ty;
            tile[k][tx] = zp[(size_t)k * HWSZ + hw0 + tx];  // coalesced
        }
        __syncthreads();
#pragma unroll
        for (int i = 0; i < 16; i++) {   // coalesced bf16 row writes
            int li = tid + i * 256;
            int ln = li >> 6, lk = li & 63;
            int n = b * HWSZ + hw0 + ln;
            zf[(size_t)n * ZD + lk] = __float2bfloat16(tile[lk][ln]);
        }
        float s = 0.f;
#pragma unroll
        for (int kk = 0; kk < 16; kk++) {
            float q = __bfloat162float(__float2bfloat16(tile[ty * 1 + kk * 4][tx]));
            s += q * q;
        }
        part[ty][tx] = s;
        __syncthreads();
        if (tid < 64) {
            float t = part[0][tid] + part[1][tid] + part[2][tid] + part[3][tid];
            zn2[b * HWSZ + hw0 + tid] = t;
        }
    } else {
        // ---- e prep + init ----
        int eb  = blk - 256;            // 0..1023
        int gid = eb * 256 + tid;
        if (gid < MM) {                 // ws is poisoned 0xAA each launch
            bmax[gid] = 0u;             // belong*d >= 0 -> uint max works
            dmin[gid] = 0x7f800000u;    // +inf
            sume[gid] = 0.f;
        }
        int wave = tid >> 6, lane = tid & 63;
        int row = eb * 4 + wave;
        if (row < MM) {
            float v = e[row * ZD + lane];
            __hip_bfloat16 b16 = __float2bfloat16(v);
            ebf[row * ZD + lane] = b16;
            float q = __bfloat162float(b16);  // norm from quantized value
            float s = q * q;
            for (int off = 32; off; off >>= 1) s += __shfl_xor(s, off);
            if (lane == 0) en2[row] = s;
        }
    }
}

// ---------------------------------------------------------------------------
// k_pass1: SWAPPED operand order (A = ebf rows m, B = zf rows n) so that
// D: row = m = lq*4 + reg  (4 CONSECUTIVE m per lane) ; col = n = l16.
// => belong[n][m..m+3] is one float4 nontemporal load per (im,jn);
//    one wave instruction covers 16 full 64B lines (1 KiB).
// Block 256 thr = 4 waves (2m x 2n); block tile 64m x 128n;
// wave tile 32m (im=0..1) x 64n (jn=0..3); K=64 via 2 chained mfma.
// Outputs: bmax[m] = max_n belong*d (uint-as-float), dmin[m] = min_n d.
// ---------------------------------------------------------------------------
__global__ __launch_bounds__(256) void k_pass1(const __hip_bfloat16* __restrict__ zf,
                                               const __hip_bfloat16* __restrict__ ebf,
                                               const float* __restrict__ zn2,
                                               const float* __restrict__ en2,
                                               const float* __restrict__ belong,
                                               unsigned* __restrict__ bmax,
                                               unsigned* __restrict__ dmin) {
    int tid = threadIdx.x;
    int wave = tid >> 6, lane = tid & 63;
    int l16 = lane & 15, lq = lane >> 4;
    int wm = wave & 1, wn = wave >> 1;
    int m0 = blockIdx.x * 64 + wm * 32;
    int n0 = blockIdx.y * 128 + wn * 64;

    const bf16x8* ebv = reinterpret_cast<const bf16x8*>(ebf);
    const bf16x8* zfv = reinterpret_cast<const bf16x8*>(zf);

    bf16x8 Af[2][2], Bf[4][2];
#pragma unroll
    for (int im = 0; im < 2; im++)
#pragma unroll
        for (int h = 0; h < 2; h++)
            Af[im][h] = ebv[(size_t)(m0 + im * 16 + l16) * 8 + h * 4 + lq];
#pragma unroll
    for (int jn = 0; jn < 4; jn++)
#pragma unroll
        for (int h = 0; h < 2; h++)
            Bf[jn][h] = zfv[(size_t)(n0 + jn * 16 + l16) * 8 + h * 4 + lq];

    // belong loads: float4 per (im, jn), nontemporal (read-once stream)
    f32x4 bl[2][4];
#pragma unroll
    for (int im = 0; im < 2; im++)
#pragma unroll
        for (int jn = 0; jn < 4; jn++) {
            const f32x4* bp = reinterpret_cast<const f32x4*>(
                belong + (size_t)(n0 + jn * 16 + l16) * MM + (m0 + im * 16 + lq * 4));
            bl[im][jn] = __builtin_nontemporal_load(bp);
        }

    f32x4 acc[2][4];
#pragma unroll
    for (int im = 0; im < 2; im++)
#pragma unroll
        for (int jn = 0; jn < 4; jn++) {
            acc[im][jn] = (f32x4){0.f, 0.f, 0.f, 0.f};
            acc[im][jn] = __builtin_amdgcn_mfma_f32_16x16x32_bf16(Af[im][0], Bf[jn][0], acc[im][jn], 0, 0, 0);
            acc[im][jn] = __builtin_amdgcn_mfma_f32_16x16x32_bf16(Af[im][1], Bf[jn][1], acc[im][jn], 0, 0, 0);
        }

    f32x4 en2v[2];
#pragma unroll
    for (int im = 0; im < 2; im++)
        en2v[im] = *reinterpret_cast<const f32x4*>(en2 + m0 + im * 16 + lq * 4);
    float zn2v[4];
#pragma unroll
    for (int jn = 0; jn < 4; jn++)
        zn2v[jn] = zn2[n0 + jn * 16 + l16];

    float vmax[2][4], vmin[2][4];
#pragma unroll
    for (int im = 0; im < 2; im++)
#pragma unroll
        for (int r = 0; r < 4; r++) { vmax[im][r] = 0.f; vmin[im][r] = 3.4e38f; }

#pragma unroll
    for (int im = 0; im < 2; im++)
#pragma unroll
        for (int jn = 0; jn < 4; jn++)
#pragma unroll
            for (int r = 0; r < 4; r++) {
                float d2 = en2v[im][r] + zn2v[jn] - 2.f * acc[im][jn][r];
                float d = sqrtf(fmaxf(d2, 0.f));
                vmax[im][r] = fmaxf(vmax[im][r], bl[im][jn][r] * d);
                vmin[im][r] = fminf(vmin[im][r], d);
            }

    // reduce across the 16 l16 lanes (n direction) within each quad
#pragma unroll
    for (int off = 1; off < 16; off <<= 1)
#pragma unroll
        for (int im = 0; im < 2; im++)
#pragma unroll
            for (int r = 0; r < 4; r++) {
                vmax[im][r] = fmaxf(vmax[im][r], __shfl_xor(vmax[im][r], off));
                vmin[im][r] = fminf(vmin[im][r], __shfl_xor(vmin[im][r], off));
            }

    __shared__ unsigned smax[64], smin[64];
    if (tid < 64) { smax[tid] = 0u; smin[tid] = 0x7f800000u; }
    __syncthreads();
    if (l16 == 0) {
#pragma unroll
        for (int im = 0; im < 2; im++)
#pragma unroll
            for (int r = 0; r < 4; r++) {
                int ml = wm * 32 + im * 16 + lq * 4 + r;
                atomicMax(&smax[ml], __float_as_uint(vmax[im][r]));
                atomicMin(&smin[ml], __float_as_uint(vmin[im][r]));
            }
    }
    __syncthreads();
    if (tid < 64) {
        atomicMax(&bmax[blockIdx.x * 64 + tid], smax[tid]);
        atomicMin(&dmin[blockIdx.x * 64 + tid], smin[tid]);
    }
}

// ---------------------------------------------------------------------------
// k_pass2: recompute d^2 (original orientation: D col = m), inline the
// new_max/ref computation per block (deterministic => identical across
// blocks), transform WITHOUT sqrt in the hot branch (compare d^2 vs nm^2),
// accumulate sum_exp[m] += exp(alpha*t - ref).
// Block x==0 materializes refs[] for k_final.
// ---------------------------------------------------------------------------
__global__ __launch_bounds__(256) void k_pass2(const __hip_bfloat16* __restrict__ zf,
                                               const __hip_bfloat16* __restrict__ ebf,
                                               const float* __restrict__ zn2,
                                               const float* __restrict__ en2,
                                               const unsigned* __restrict__ bmax,
                                               const unsigned* __restrict__ dmin,
                                               const float* __restrict__ max_distance,
                                               const float* __restrict__ log_sigma,
                                               const int* __restrict__ pp,
                                               float* __restrict__ refs,
                                               float* __restrict__ sume) {
    __shared__ float snm2[128], sref[128], ssum[128];
    int tid = threadIdx.x;
    int wave = tid >> 6, lane = tid & 63;
    int l16 = lane & 15, lq = lane >> 4;
    int wn = wave >> 1, wm = wave & 1;
    int n0 = blockIdx.x * 64 + wn * 32;
    int m0 = blockIdx.y * 128 + wm * 64;

    int p = pp[0];
    float alpha = -0.5f * __expf(-2.f * log_sigma[0]);

    if (tid < 128) {
        int m = blockIdx.y * 128 + tid;
        float bm = __uint_as_float(bmax[m]);
        float dm = __uint_as_float(dmin[m]);
        float nm = fmaxf(EMA_C * max_distance[m] + (1.f - EMA_C) * bm, EPS_C);
        float tlow;
        if (p == 2) {
            float d4  = (dm * dm) * (dm * dm);
            float nm4 = (nm * nm) * (nm * nm);
            tlow = (dm < nm) ? fminf(dm, nm4) : d4;
        } else {
            float e1 = 2.f / (float)p, e2 = 2.f * (float)p;
            tlow = (dm < nm) ? fminf(powf(dm, e1), powf(nm, e2)) : powf(dm, e2);
        }
        float rf = alpha * tlow;   // alpha<0, t>=tlow => s<=rf (no overflow)
        snm2[tid] = nm * nm;
        sref[tid] = rf;
        ssum[tid] = 0.f;
        if (blockIdx.x == 0) refs[m] = rf;
    }
    __syncthreads();

    const bf16x8* zfv = reinterpret_cast<const bf16x8*>(zf);
    const bf16x8* ebv = reinterpret_cast<const bf16x8*>(ebf);

    bf16x8 Af[2][2], Bf[4][2];
#pragma unroll
    for (int i = 0; i < 2; i++)
#pragma unroll
        for (int h = 0; h < 2; h++)
            Af[i][h] = zfv[(size_t)(n0 + i * 16 + l16) * 8 + h * 4 + lq];
#pragma unroll
    for (int j = 0; j < 4; j++)
#pragma unroll
        for (int h = 0; h < 2; h++)
            Bf[j][h] = ebv[(size_t)(m0 + j * 16 + l16) * 8 + h * 4 + lq];

    f32x4 acc[2][4];
#pragma unroll
    for (int i = 0; i < 2; i++)
#pragma unroll
        for (int j = 0; j < 4; j++) {
            acc[i][j] = (f32x4){0.f, 0.f, 0.f, 0.f};
            acc[i][j] = __builtin_amdgcn_mfma_f32_16x16x32_bf16(Af[i][0], Bf[j][0], acc[i][j], 0, 0, 0);
            acc[i][j] = __builtin_amdgcn_mfma_f32_16x16x32_bf16(Af[i][1], Bf[j][1], acc[i][j], 0, 0, 0);
        }

    f32x4 zn2v[2];
#pragma unroll
    for (int i = 0; i < 2; i++)
        zn2v[i] = *reinterpret_cast<const f32x4*>(zn2 + n0 + i * 16 + lq * 4);

    bool p2 = (p == 2);
    float pe = (float)p, pi = 1.f / (float)p;

#pragma unroll
    for (int j = 0; j < 4; j++) {
        float en2v = en2[m0 + j * 16 + l16];
        float nm2v = snm2[wm * 64 + j * 16 + l16];
        float rfv  = sref[wm * 64 + j * 16 + l16];
        float csum = 0.f;
#pragma unroll
        for (int i = 0; i < 2; i++)
#pragma unroll
            for (int r = 0; r < 4; r++) {
                float d2c = fmaxf(zn2v[i][r] + en2v - 2.f * acc[i][j][r], 0.f);
                float t;
                if (p2) t = (d2c < nm2v) ? sqrtf(d2c) : d2c * d2c;   // d^1 / d^4
                else    t = powf(d2c, (d2c < nm2v) ? pi : pe);       // (d^2)^(1/p) / (d^2)^p
                csum += __expf(fmaf(alpha, t, -rfv));
            }
        csum += __shfl_xor(csum, 16);
        csum += __shfl_xor(csum, 32);
        if (lane < 16) atomicAdd(&ssum[wm * 64 + j * 16 + lane], csum);
    }
    __syncthreads();
    if (tid < 128) atomicAdd(&sume[blockIdx.y * 128 + tid], ssum[tid]);
}

// ---------------------------------------------------------------------------
// k_final: loss = -mean(ref + log(sum_exp)) + z_dim * log_sigma
// ---------------------------------------------------------------------------
__global__ __launch_bounds__(256) void k_final(const float* __restrict__ refs,
                                               const float* __restrict__ sume,
                                               const float* __restrict__ log_sigma,
                                               float* __restrict__ out) {
    __shared__ float red[4];
    int tid = threadIdx.x;
    float a = 0.f;
    for (int m = tid; m < MM; m += 256)
        a += refs[m] + logf(fmaxf(sume[m], 1e-30f));
    for (int off = 32; off; off >>= 1) a += __shfl_xor(a, off);
    int wave = tid >> 6, lane = tid & 63;
    if (lane == 0) red[wave] = a;
    __syncthreads();
    if (tid == 0) {
        float t = red[0] + red[1] + red[2] + red[3];
        out[0] = -t / (float)MM + (float)ZD * log_sigma[0];
    }
}

// ---------------------------------------------------------------------------
extern "C" void kernel_launch(void* const* d_in, const int* in_sizes, int n_in,
                              void* d_out, int out_size, void* d_ws, size_t ws_size,
                              hipStream_t stream) {
    const float* z            = (const float*)d_in[0];
    const float* e            = (const float*)d_in[1];
    const float* belong       = (const float*)d_in[2];
    const float* log_sigma    = (const float*)d_in[3];
    const float* max_distance = (const float*)d_in[4];
    const int*   pp           = (const int*)d_in[5];
    float* out = (float*)d_out;

    char* ws = (char*)d_ws;
    __hip_bfloat16* zf  = (__hip_bfloat16*)(ws + 0);        // 2,097,152 B
    __hip_bfloat16* ebf = (__hip_bfloat16*)(ws + 2097152);  //   524,288 B
    float*    zn2  = (float*)(ws + 2621440);                //    65,536 B
    float*    en2  = (float*)(ws + 2686976);                //    16,384 B
    unsigned* bmax = (unsigned*)(ws + 2703360);             //    16,384 B
    unsigned* dmin = (unsigned*)(ws + 2719744);             //    16,384 B
    float*    refs = (float*)(ws + 2736128);                //    16,384 B
    float*    sume = (float*)(ws + 2752512);                //    16,384 B

    k_prep<<<1280, 256, 0, stream>>>(z, e, zf, ebf, zn2, en2, bmax, dmin, sume);
    k_pass1<<<dim3(MM / 64, NN / 128), 256, 0, stream>>>(zf, ebf, zn2, en2, belong, bmax, dmin);
    k_pass2<<<dim3(NN / 64, MM / 128), 256, 0, stream>>>(zf, ebf, zn2, en2, bmax, dmin,
                                                         max_distance, log_sigma, pp, refs, sume);
    k_final<<<1, 256, 0, stream>>>(refs, sume, log_sigma, out);
}